// Round 2
// baseline (1348.263 us; speedup 1.0000x reference)
//
#include <hip/hip_runtime.h>

typedef __attribute__((ext_vector_type(8))) short short8;
typedef __attribute__((ext_vector_type(16))) float f32x16;
typedef __attribute__((ext_vector_type(4))) unsigned uint4v;

#define NT 512

template<int N> struct IC { static constexpr int v = N; };

static __device__ __forceinline__ unsigned packbf(float hi, float lo) {
    return __builtin_amdgcn_perm(__float_as_uint(hi) + 0x8000u,
                                 __float_as_uint(lo) + 0x8000u, 0x07060302u);
}
static __device__ __forceinline__ short one_bf(float f) {
    return (short)((__float_as_uint(f) + 0x8000u) >> 16);
}
static __device__ __forceinline__ float bflo(unsigned u) { return __uint_as_float(u << 16); }
static __device__ __forceinline__ float bfhi(unsigned u) { return __uint_as_float(u & 0xffff0000u); }

static __device__ __forceinline__ int swz(int row, int c) {
    return (row * 128 + c) ^ ((row & 7) << 3);
}

__global__ __launch_bounds__(512, 2)
void vgt_kernel(const int* __restrict__ x,
                const float* __restrict__ emb_w,
                const float* __restrict__ red_w,
                const float* __restrict__ red_b,
                const float* __restrict__ conv_w,
                const float* __restrict__ conv_b,
                const float* __restrict__ out_w,
                const float* __restrict__ out_b,
                float* __restrict__ out)
{
    __shared__ short    hb[144 * 128];   // bf16 h image, swizzled rows (36864 B)
    __shared__ float    m1[128][10];
    __shared__ float    m2[128][10];
    __shared__ unsigned owP[10][64];     // packed bf16 head weights
    __shared__ float    cbS[128];
    __shared__ float    rbS[128];
    __shared__ float    obS[16];
    __shared__ int      xbS[256];

    const int b    = blockIdx.x;
    const int tid  = threadIdx.x;
    const int lane = tid & 63;
    const int wv   = tid >> 6;
    const int wm   = wv & 3;
    const int wh   = wv >> 2;
    const int obase = wm * 32;
    const int tbase = wh * 64;
    const int l31  = lane & 31;
    const int lhi  = lane >> 5;

    // ---------------- prologue ----------------
    for (int i = tid; i < 144 * 128 / 2; i += NT) ((int*)hb)[i] = 0;
    if (tid < 256) xbS[tid] = x[b * 256 + tid];
    if (tid < 128) { cbS[tid] = conv_b[tid]; rbS[tid] = red_b[tid]; }
    if (tid < 16)  obS[tid] = (tid < 10) ? out_b[tid] : 0.f;
    for (int i = tid; i < 640; i += NT) {
        int v = i >> 6, j = i & 63;
        owP[v][j] = packbf(out_w[v * 128 + 2 * j + 1], out_w[v * 128 + 2 * j]);
    }
    // embedding + reducer collapsed into two 128x10 tables (float4 dots)
    for (int e = tid; e < 2560; e += NT) {
        int o = e / 20, col = e % 20, v = col % 10;
        const float4* rw = (const float4*)(red_w + o * 256 + ((col < 10) ? 0 : 128));
        const float4* ew = (const float4*)(emb_w + v * 128);
        float s = 0.f;
#pragma unroll 8
        for (int c = 0; c < 32; ++c) {
            float4 a = rw[c], e4 = ew[c];
            s += a.x * e4.x + a.y * e4.y + a.z * e4.z + a.w * e4.w;
        }
        if (col < 10) m1[o][v] = s; else m2[o][v] = s;
    }

    // A fragments (conv weights) resident in registers: s = kk*8 + cb
    short8 aw[24];
#pragma unroll
    for (int s = 0; s < 24; ++s) {
        int kk = s >> 3, cb = s & 7;
        int o = obase + l31;
        int c0 = cb * 16 + lhi * 8;
        short8 v;
#pragma unroll
        for (int j = 0; j < 8; ++j)
            v[j] = one_bf(conv_w[(o * 128 + c0 + j) * 3 + kk]);
        aw[s] = v;
    }

    // tail-column weights (t=128): thread -> o_t = tid>>2, channels [32q, 32q+32)
    const int o_t = tid >> 2, q = tid & 3;
    unsigned twA[16], twB[16];
#pragma unroll
    for (int i = 0; i < 16; ++i) {
        int c = q * 32 + 2 * i;
        twA[i] = packbf(__builtin_bit_cast(float, __float_as_uint(conv_w[(o_t*128 + c + 1)*3 + 0])),
                        conv_w[(o_t*128 + c)*3 + 0]);
        twB[i] = packbf(conv_w[(o_t*128 + c + 1)*3 + 1], conv_w[(o_t*128 + c)*3 + 1]);
        // fix twA hi arg (plain float)
        twA[i] = packbf(conv_w[(o_t*128 + c + 1)*3 + 0], conv_w[(o_t*128 + c)*3 + 0]);
    }
    float h128reg = 0.f;

    __syncthreads();

    const float cb_t = cbS[o_t];

    // bias fragment in registers (C-layout), used as accumulator init
    f32x16 biasv;
#pragma unroll
    for (int r = 0; r < 16; ++r)
        biasv[r] = cbS[obase + (r & 3) + 8 * (r >> 2) + 4 * lhi];

    // initial h (fp32 master in registers, C-fragment layout)
    float hr[2][16];
#pragma unroll
    for (int nn = 0; nn < 2; ++nn) {
        int t = tbase + nn * 32 + l31;
        int xv1 = xbS[t], xv2 = xbS[t + 128];
#pragma unroll
        for (int r = 0; r < 16; ++r) {
            int o = obase + (r & 3) + 8 * (r >> 2) + 4 * lhi;
            float s = m1[o][xv1] + m2[o][xv2] + rbS[o];
            hr[nn][r] = s > 0.f ? s : 0.f;
        }
    }
#pragma unroll
    for (int nn = 0; nn < 2; ++nn) {
        int row = tbase + nn * 32 + l31 + 4;
#pragma unroll
        for (int g = 0; g < 4; ++g) {
            int o = obase + 8 * g + 4 * lhi;
            unsigned lo = packbf(hr[nn][4*g+1], hr[nn][4*g+0]);
            unsigned hi = packbf(hr[nn][4*g+3], hr[nn][4*g+2]);
            *(uint2*)&hb[swz(row, o)] = make_uint2(lo, hi);
        }
    }
    __syncthreads();

    // ---------------- residual conv step (dd compile-time) ----------------
    auto step = [&](auto DDC) {
        constexpr int DD = decltype(DDC)::v;
        f32x16 a0 = biasv, a1 = biasv;
        const int base0 = tbase + l31 + 4;
#pragma unroll
        for (int s = 0; s < 24; ++s) {
            const int kk = s >> 3, cb = s & 7;
            const int r0 = base0 + (kk - 1) * DD;
            const int r1 = r0 + 32;
            const int c0 = cb * 16 + lhi * 8;
            short8 b0 = *(const short8*)&hb[swz(r0, c0)];
            short8 b1 = *(const short8*)&hb[swz(r1, c0)];
            a0 = __builtin_amdgcn_mfma_f32_32x32x16_bf16(aw[s], b0, a0, 0, 0, 0);
            a1 = __builtin_amdgcn_mfma_f32_32x32x16_bf16(aw[s], b1, a1, 0, 0, 0);
        }

        // tail column t=128: taps k=0 (row 132-DD) and k=1 (row 132); k=2 is pad zero
        float tsum = 0.f;
        {
            const int rowA = 132 - DD;
#pragma unroll
            for (int j = 0; j < 4; ++j) {
                uint4v va = *(const uint4v*)&hb[swz(rowA, 32 * q + 8 * j)];
                uint4v vb = *(const uint4v*)&hb[swz(132,  32 * q + 8 * j)];
#pragma unroll
                for (int i = 0; i < 4; ++i) {
                    unsigned wa = twA[4*j+i], wb = twB[4*j+i];
                    tsum += bflo(va[i]) * bflo(wa) + bfhi(va[i]) * bfhi(wa)
                          + bflo(vb[i]) * bflo(wb) + bfhi(vb[i]) * bfhi(wb);
                }
            }
        }
        tsum += __shfl_xor(tsum, 1);
        tsum += __shfl_xor(tsum, 2);
        float h128new = 0.f;
        if (q == 0) h128new = fmaxf(tsum + cb_t, 0.f) + h128reg;

        __syncthreads();   // all reads of hb done

#pragma unroll
        for (int nn = 0; nn < 2; ++nn) {
            const int row = tbase + nn * 32 + l31 + 4;
#pragma unroll
            for (int g = 0; g < 4; ++g) {
                float v0 = (nn == 0) ? a0[4*g+0] : a1[4*g+0];
                float v1 = (nn == 0) ? a0[4*g+1] : a1[4*g+1];
                float v2 = (nn == 0) ? a0[4*g+2] : a1[4*g+2];
                float v3 = (nn == 0) ? a0[4*g+3] : a1[4*g+3];
                hr[nn][4*g+0] += fmaxf(v0, 0.f);
                hr[nn][4*g+1] += fmaxf(v1, 0.f);
                hr[nn][4*g+2] += fmaxf(v2, 0.f);
                hr[nn][4*g+3] += fmaxf(v3, 0.f);
                unsigned lo = packbf(hr[nn][4*g+1], hr[nn][4*g+0]);
                unsigned hi = packbf(hr[nn][4*g+3], hr[nn][4*g+2]);
                *(uint2*)&hb[swz(row, obase + 8 * g + 4 * lhi)] = make_uint2(lo, hi);
            }
        }
        if (q == 0) {
            h128reg = h128new;
            hb[swz(132, o_t)] = one_bf(h128reg);
        }
        __syncthreads();
    };

    for (int i = 0; i < 4;   ++i) step(IC<1>{});
    for (int i = 0; i < 4;   ++i) step(IC<2>{});
    for (int i = 0; i < 123; ++i) step(IC<4>{});

    // ---------------- output head ----------------
    const int g = tid & 3;
    for (int tt = tid >> 2; tt < 129; tt += 128) {
        const int row = tt + 4;
        float hq[32];
#pragma unroll
        for (int j = 0; j < 4; ++j) {
            uint4v v = *(const uint4v*)&hb[swz(row, 32 * g + 8 * j)];
#pragma unroll
            for (int i = 0; i < 4; ++i) {
                hq[j*8 + 2*i]     = bflo(v[i]);
                hq[j*8 + 2*i + 1] = bfhi(v[i]);
            }
        }
#pragma unroll
        for (int v = 0; v < 10; ++v) {
            float s = 0.f;
#pragma unroll
            for (int i = 0; i < 16; ++i) {
                unsigned w = owP[v][16 * g + i];
                s += hq[2*i] * bflo(w) + hq[2*i + 1] * bfhi(w);
            }
            s += __shfl_xor(s, 1);
            s += __shfl_xor(s, 2);
            if (g == 0) out[(b * 129 + tt) * 10 + v] = s + obS[v];
        }
    }
}

extern "C" void kernel_launch(void* const* d_in, const int* in_sizes, int n_in,
                              void* d_out, int out_size, void* d_ws, size_t ws_size,
                              hipStream_t stream) {
    const int*   x      = (const int*)d_in[0];
    const float* emb_w  = (const float*)d_in[1];
    const float* red_w  = (const float*)d_in[2];
    const float* red_b  = (const float*)d_in[3];
    const float* conv_w = (const float*)d_in[4];
    const float* conv_b = (const float*)d_in[5];
    const float* out_w  = (const float*)d_in[6];
    const float* out_b  = (const float*)d_in[7];
    (void)in_sizes; (void)n_in; (void)d_ws; (void)ws_size; (void)out_size;
    vgt_kernel<<<32, 512, 0, stream>>>(x, emb_w, red_w, red_b, conv_w, conv_b,
                                       out_w, out_b, (float*)d_out);
}

// Round 4
// 1338.731 us; speedup vs baseline: 1.0071x; 1.0071x over previous
//
#include <hip/hip_runtime.h>

typedef __attribute__((ext_vector_type(8))) short short8;
typedef __attribute__((ext_vector_type(16))) float f32x16;
typedef __attribute__((ext_vector_type(4))) unsigned uint4v;

#define NT 512
#define HROWS 144
#define HSTRIDE (HROWS * 128)   // shorts per buffer

template<int N> struct IC { static constexpr int v = N; };

static __device__ __forceinline__ unsigned packbf(float hi, float lo) {
    return __builtin_amdgcn_perm(__float_as_uint(hi) + 0x8000u,
                                 __float_as_uint(lo) + 0x8000u, 0x07060302u);
}
static __device__ __forceinline__ short one_bf(float f) {
    return (short)((__float_as_uint(f) + 0x8000u) >> 16);
}
static __device__ __forceinline__ float bflo(unsigned u) { return __uint_as_float(u << 16); }
static __device__ __forceinline__ float bfhi(unsigned u) { return __uint_as_float(u & 0xffff0000u); }

static __device__ __forceinline__ int swz(int row, int c) {
    return (row * 128 + c) ^ ((row & 7) << 3);
}

__global__ __launch_bounds__(512, 1)
void vgt_kernel(const int* __restrict__ x,
                const float* __restrict__ emb_w,
                const float* __restrict__ red_w,
                const float* __restrict__ red_b,
                const float* __restrict__ conv_w,
                const float* __restrict__ conv_b,
                const float* __restrict__ out_w,
                const float* __restrict__ out_b,
                float* __restrict__ out)
{
    __shared__ short    hbuf[2 * HSTRIDE];   // ping-pong bf16 h images (73728 B)
    __shared__ float    m1[128][10];
    __shared__ float    m2[128][10];
    __shared__ unsigned owP[10][64];
    __shared__ float    cbS[128];
    __shared__ float    rbS[128];
    __shared__ float    obS[16];
    __shared__ int      xbS[256];

    const int b    = blockIdx.x;
    const int tid  = threadIdx.x;
    const int lane = tid & 63;
    const int wv   = tid >> 6;
    const int wm   = wv & 3;
    const int wh   = wv >> 2;
    const int obase = wm * 32;
    const int tbase = wh * 64;
    const int l31  = lane & 31;
    const int lhi  = lane >> 5;

    // ---------------- prologue ----------------
    for (int i = tid; i < 2 * HSTRIDE / 2; i += NT) ((int*)hbuf)[i] = 0;
    if (tid < 256) xbS[tid] = x[b * 256 + tid];
    if (tid < 128) { cbS[tid] = conv_b[tid]; rbS[tid] = red_b[tid]; }
    if (tid < 16)  obS[tid] = (tid < 10) ? out_b[tid] : 0.f;
    for (int i = tid; i < 640; i += NT) {
        int v = i >> 6, j = i & 63;
        owP[v][j] = packbf(out_w[v * 128 + 2 * j + 1], out_w[v * 128 + 2 * j]);
    }
    // embedding + reducer collapsed into two 128x10 tables
    for (int e = tid; e < 2560; e += NT) {
        int o = e / 20, col = e % 20, v = col % 10;
        const float4* rw = (const float4*)(red_w + o * 256 + ((col < 10) ? 0 : 128));
        const float4* ew = (const float4*)(emb_w + v * 128);
        float s = 0.f;
#pragma unroll 8
        for (int c = 0; c < 32; ++c) {
            float4 a = rw[c], e4 = ew[c];
            s += a.x * e4.x + a.y * e4.y + a.z * e4.z + a.w * e4.w;
        }
        if (col < 10) m1[o][v] = s; else m2[o][v] = s;
    }

    // conv-weight A fragments resident in registers: s = kk*8 + cb (96 VGPR)
    short8 aw[24];
#pragma unroll
    for (int s = 0; s < 24; ++s) {
        int kk = s >> 3, cb = s & 7;
        int o = obase + l31;
        int c0 = cb * 16 + lhi * 8;
        short8 v;
#pragma unroll
        for (int j = 0; j < 8; ++j)
            v[j] = one_bf(conv_w[(o * 128 + c0 + j) * 3 + kk]);
        aw[s] = v;
    }

    // tail column (t=128): 4 threads per o; q owns 32-channel block, BOTH taps
    const int o_t = tid >> 2, q = tid & 3;
    unsigned twA[16], twB[16];
#pragma unroll
    for (int i = 0; i < 16; ++i) {
        int c = q * 32 + 2 * i;
        twA[i] = packbf(conv_w[(o_t * 128 + c + 1) * 3 + 0],
                        conv_w[(o_t * 128 + c) * 3 + 0]);
        twB[i] = packbf(conv_w[(o_t * 128 + c + 1) * 3 + 1],
                        conv_w[(o_t * 128 + c) * 3 + 1]);
    }
    float h128reg = 0.f;

    __syncthreads();

    const float cb_t = cbS[o_t];

    // bias fragment (C-layout) used as accumulator init
    f32x16 biasv;
#pragma unroll
    for (int r = 0; r < 16; ++r)
        biasv[r] = cbS[obase + (r & 3) + 8 * (r >> 2) + 4 * lhi];

    // initial h (fp32 master in registers, C-fragment layout)
    float hr[2][16];
#pragma unroll
    for (int nn = 0; nn < 2; ++nn) {
        int t = tbase + nn * 32 + l31;
        int xv1 = xbS[t], xv2 = xbS[t + 128];
#pragma unroll
        for (int r = 0; r < 16; ++r) {
            int o = obase + (r & 3) + 8 * (r >> 2) + 4 * lhi;
            float s = m1[o][xv1] + m2[o][xv2] + rbS[o];
            hr[nn][r] = s > 0.f ? s : 0.f;
        }
    }
#pragma unroll
    for (int nn = 0; nn < 2; ++nn) {
        int row = tbase + nn * 32 + l31 + 4;
#pragma unroll
        for (int g = 0; g < 4; ++g) {
            int o = obase + 8 * g + 4 * lhi;
            unsigned lo = packbf(hr[nn][4*g+1], hr[nn][4*g+0]);
            unsigned hi = packbf(hr[nn][4*g+3], hr[nn][4*g+2]);
            *(uint2*)&hbuf[swz(row, o)] = make_uint2(lo, hi);
        }
    }
    __syncthreads();

    // ------------- residual conv step: read src, write dst, ONE barrier -------------
    auto step = [&](auto DDC, int cur) {
        constexpr int DD = decltype(DDC)::v;
        const short* src = hbuf + cur * HSTRIDE;
        short*       dst = hbuf + (cur ^ 1) * HSTRIDE;

        f32x16 a0 = biasv, a1 = biasv;
        const int base0 = tbase + l31 + 4;
#pragma unroll
        for (int s = 0; s < 24; ++s) {
            const int kk = s >> 3, cb = s & 7;
            const int r0 = base0 + (kk - 1) * DD;
            const int r1 = r0 + 32;
            const int c0 = cb * 16 + lhi * 8;
            short8 b0 = *(const short8*)&src[swz(r0, c0)];
            short8 b1 = *(const short8*)&src[swz(r1, c0)];
            a0 = __builtin_amdgcn_mfma_f32_32x32x16_bf16(aw[s], b0, a0, 0, 0, 0);
            a1 = __builtin_amdgcn_mfma_f32_32x32x16_bf16(aw[s], b1, a1, 0, 0, 0);
        }

        // tail column t=128: q's 32-channel block, taps k=0 (row 132-DD) and k=1 (row 132)
        float tsum = 0.f;
        {
            const int rowA = 132 - DD;
#pragma unroll
            for (int j = 0; j < 4; ++j) {
                uint4v va = *(const uint4v*)&src[swz(rowA, 32 * q + 8 * j)];
                uint4v vb = *(const uint4v*)&src[swz(132,  32 * q + 8 * j)];
#pragma unroll
                for (int i = 0; i < 4; ++i) {
                    unsigned wa = twA[4*j+i], wb = twB[4*j+i];
                    tsum += bflo(va[i]) * bflo(wa) + bfhi(va[i]) * bfhi(wa)
                          + bflo(vb[i]) * bflo(wb) + bfhi(vb[i]) * bfhi(wb);
                }
            }
        }
        tsum += __shfl_xor(tsum, 1);
        tsum += __shfl_xor(tsum, 2);
        if (q == 0) {
            h128reg = fmaxf(tsum + cb_t, 0.f) + h128reg;
            dst[swz(132, o_t)] = one_bf(h128reg);
        }

        // h := relu(conv) + h ; write new bf16 image into dst
#pragma unroll
        for (int nn = 0; nn < 2; ++nn) {
            const int row = tbase + nn * 32 + l31 + 4;
#pragma unroll
            for (int g = 0; g < 4; ++g) {
                float v0 = (nn == 0) ? a0[4*g+0] : a1[4*g+0];
                float v1 = (nn == 0) ? a0[4*g+1] : a1[4*g+1];
                float v2 = (nn == 0) ? a0[4*g+2] : a1[4*g+2];
                float v3 = (nn == 0) ? a0[4*g+3] : a1[4*g+3];
                hr[nn][4*g+0] += fmaxf(v0, 0.f);
                hr[nn][4*g+1] += fmaxf(v1, 0.f);
                hr[nn][4*g+2] += fmaxf(v2, 0.f);
                hr[nn][4*g+3] += fmaxf(v3, 0.f);
                unsigned lo = packbf(hr[nn][4*g+1], hr[nn][4*g+0]);
                unsigned hi = packbf(hr[nn][4*g+3], hr[nn][4*g+2]);
                *(uint2*)&dst[swz(row, obase + 8 * g + 4 * lhi)] = make_uint2(lo, hi);
            }
        }
        __syncthreads();
    };

    int cur = 0;
    for (int i = 0; i < 4;   ++i) { step(IC<1>{}, cur); cur ^= 1; }
    for (int i = 0; i < 4;   ++i) { step(IC<2>{}, cur); cur ^= 1; }
    for (int i = 0; i < 123; ++i) { step(IC<4>{}, cur); cur ^= 1; }

    // ---------------- output head ----------------
    const short* fin = hbuf + cur * HSTRIDE;
    const int g = tid & 3;
    for (int tt = tid >> 2; tt < 129; tt += 128) {
        const int row = tt + 4;
        float hq[32];
#pragma unroll
        for (int j = 0; j < 4; ++j) {
            uint4v v = *(const uint4v*)&fin[swz(row, 32 * g + 8 * j)];
#pragma unroll
            for (int i = 0; i < 4; ++i) {
                hq[j*8 + 2*i]     = bflo(v[i]);
                hq[j*8 + 2*i + 1] = bfhi(v[i]);
            }
        }
#pragma unroll
        for (int v = 0; v < 10; ++v) {
            float s = 0.f;
#pragma unroll
            for (int i = 0; i < 16; ++i) {
                unsigned w = owP[v][16 * g + i];
                s += hq[2*i] * bflo(w) + hq[2*i + 1] * bfhi(w);
            }
            s += __shfl_xor(s, 1);
            s += __shfl_xor(s, 2);
            if (g == 0) out[(b * 129 + tt) * 10 + v] = s + obS[v];
        }
    }
}

extern "C" void kernel_launch(void* const* d_in, const int* in_sizes, int n_in,
                              void* d_out, int out_size, void* d_ws, size_t ws_size,
                              hipStream_t stream) {
    const int*   x      = (const int*)d_in[0];
    const float* emb_w  = (const float*)d_in[1];
    const float* red_w  = (const float*)d_in[2];
    const float* red_b  = (const float*)d_in[3];
    const float* conv_w = (const float*)d_in[4];
    const float* conv_b = (const float*)d_in[5];
    const float* out_w  = (const float*)d_in[6];
    const float* out_b  = (const float*)d_in[7];
    (void)in_sizes; (void)n_in; (void)d_ws; (void)ws_size; (void)out_size;
    vgt_kernel<<<32, 512, 0, stream>>>(x, emb_w, red_w, red_b, conv_w, conv_b,
                                       out_w, out_b, (float*)d_out);
}

// Round 5
// 1007.706 us; speedup vs baseline: 1.3380x; 1.3285x over previous
//
#include <hip/hip_runtime.h>

typedef __attribute__((ext_vector_type(8))) short short8;
typedef __attribute__((ext_vector_type(4))) float vf4;
typedef __attribute__((ext_vector_type(4))) unsigned uint4v;

#define NT 1024
#define HROWS 144
#define HSTRIDE (HROWS * 128)   // shorts per buffer

template<int N> struct IC { static constexpr int v = N; };

static __device__ __forceinline__ unsigned packbf(float hi, float lo) {
    return __builtin_amdgcn_perm(__float_as_uint(hi) + 0x8000u,
                                 __float_as_uint(lo) + 0x8000u, 0x07060302u);
}
static __device__ __forceinline__ short one_bf(float f) {
    return (short)((__float_as_uint(f) + 0x8000u) >> 16);
}
static __device__ __forceinline__ float bflo(unsigned u) { return __uint_as_float(u << 16); }
static __device__ __forceinline__ float bfhi(unsigned u) { return __uint_as_float(u & 0xffff0000u); }

static __device__ __forceinline__ int swz(int row, int c) {
    return (row * 128 + c) ^ ((row & 7) << 3);
}

__global__ __launch_bounds__(1024, 1)
void vgt_kernel(const int* __restrict__ x,
                const float* __restrict__ emb_w,
                const float* __restrict__ red_w,
                const float* __restrict__ red_b,
                const float* __restrict__ conv_w,
                const float* __restrict__ conv_b,
                const float* __restrict__ out_w,
                const float* __restrict__ out_b,
                float* __restrict__ out)
{
    __shared__ short    hbuf[2 * HSTRIDE];   // ping-pong bf16 h images (73728 B)
    __shared__ float    m1[128][10];
    __shared__ float    m2[128][10];
    __shared__ unsigned owP[10][64];
    __shared__ float    cbS[128];
    __shared__ float    rbS[128];
    __shared__ float    obS[16];
    __shared__ int      xbS[256];

    const int b    = blockIdx.x;
    const int tid  = threadIdx.x;
    const int lane = tid & 63;
    const int wv   = tid >> 6;          // 0..15
    const int wm8  = wv & 7;            // M tile: 16 output channels
    const int wt2  = wv >> 3;           // t half: 64 columns
    const int mbase = wm8 * 16;
    const int tb0   = wt2 * 64;
    const int l15  = lane & 15;
    const int l4   = lane >> 4;         // 0..3

    // ---------------- prologue ----------------
    for (int i = tid; i < HSTRIDE; i += NT) ((int*)hbuf)[i] = 0;
    if (tid < 256) xbS[tid] = x[b * 256 + tid];
    if (tid < 128) { cbS[tid] = conv_b[tid]; rbS[tid] = red_b[tid]; }
    if (tid < 16)  obS[tid] = (tid < 10) ? out_b[tid] : 0.f;
    if (tid < 640) {
        int v = tid >> 6, j = tid & 63;
        owP[v][j] = packbf(out_w[v * 128 + 2 * j + 1], out_w[v * 128 + 2 * j]);
    }
    // embedding + reducer collapsed into two 128x10 tables
    for (int e = tid; e < 2560; e += NT) {
        int o = e / 20, col = e % 20, v = col % 10;
        const float4* rw = (const float4*)(red_w + o * 256 + ((col < 10) ? 0 : 128));
        const float4* ew = (const float4*)(emb_w + v * 128);
        float s = 0.f;
#pragma unroll 8
        for (int c = 0; c < 32; ++c) {
            float4 a = rw[c], e4 = ew[c];
            s += a.x * e4.x + a.y * e4.y + a.z * e4.z + a.w * e4.w;
        }
        if (col < 10) m1[o][v] = s; else m2[o][v] = s;
    }

    // conv-weight A fragments (16x16x32 layout): aw[kk*4+kb]
    // lane holds A[mbase + l15][kb*32 + l4*8 + j], tap kk   -> 48 VGPRs
    short8 aw[12];
#pragma unroll
    for (int s = 0; s < 12; ++s) {
        int kk = s >> 2, kb = s & 3;
        int o = mbase + l15;
        int c0 = kb * 32 + l4 * 8;
        short8 v;
#pragma unroll
        for (int j = 0; j < 8; ++j)
            v[j] = one_bf(conv_w[(o * 128 + c0 + j) * 3 + kk]);
        aw[s] = v;
    }

    // tail column (t=128): 8 threads per o; q8 owns 16 channels, both taps (16 regs)
    const int o_t = tid >> 3, q8 = tid & 7;
    const int tc0 = q8 * 16;
    unsigned twA[8], twB[8];
#pragma unroll
    for (int i = 0; i < 8; ++i) {
        int c = tc0 + 2 * i;
        twA[i] = packbf(conv_w[(o_t * 128 + c + 1) * 3 + 0],
                        conv_w[(o_t * 128 + c) * 3 + 0]);
        twB[i] = packbf(conv_w[(o_t * 128 + c + 1) * 3 + 1],
                        conv_w[(o_t * 128 + c) * 3 + 1]);
    }
    float h128reg = 0.f;

    __syncthreads();

    const float cb_t = cbS[o_t];
    float bias4[4];
#pragma unroll
    for (int r = 0; r < 4; ++r) bias4[r] = cbS[mbase + l4 * 4 + r];

    // initial h: fp32 master hr[st][r] covers o = mbase+4*l4+r, t = tb0+st*16+l15
    float hr[4][4];
#pragma unroll
    for (int st = 0; st < 4; ++st) {
        int t = tb0 + st * 16 + l15;
        int xv1 = xbS[t], xv2 = xbS[t + 128];
#pragma unroll
        for (int r = 0; r < 4; ++r) {
            int o = mbase + l4 * 4 + r;
            float s = m1[o][xv1] + m2[o][xv2] + rbS[o];
            hr[st][r] = s > 0.f ? s : 0.f;
        }
        int row = t + 4;
        unsigned lo = packbf(hr[st][1], hr[st][0]);
        unsigned hi = packbf(hr[st][3], hr[st][2]);
        *(uint2*)&hbuf[swz(row, mbase + 4 * l4)] = make_uint2(lo, hi);
    }
    __syncthreads();

    // ------------- residual conv step: read src, write dst, ONE barrier -------------
    auto step = [&](auto DDC, int cur) {
        constexpr int DD = decltype(DDC)::v;
        const short* src = hbuf + cur * HSTRIDE;
        short*       dst = hbuf + (cur ^ 1) * HSTRIDE;

#pragma unroll
        for (int st = 0; st < 4; ++st) {
            const int tcol = tb0 + st * 16;
            vf4 acc;
            acc[0] = bias4[0]; acc[1] = bias4[1];
            acc[2] = bias4[2]; acc[3] = bias4[3];
#pragma unroll
            for (int kk = 0; kk < 3; ++kk) {
                const int row = tcol + l15 + 4 + (kk - 1) * DD;
#pragma unroll
                for (int kb = 0; kb < 4; ++kb) {
                    short8 bfr = *(const short8*)&src[swz(row, kb * 32 + l4 * 8)];
                    acc = __builtin_amdgcn_mfma_f32_16x16x32_bf16(aw[kk * 4 + kb], bfr, acc, 0, 0, 0);
                }
            }
            const int row = tcol + l15 + 4;
            hr[st][0] += fmaxf(acc[0], 0.f);
            hr[st][1] += fmaxf(acc[1], 0.f);
            hr[st][2] += fmaxf(acc[2], 0.f);
            hr[st][3] += fmaxf(acc[3], 0.f);
            unsigned lo = packbf(hr[st][1], hr[st][0]);
            unsigned hi = packbf(hr[st][3], hr[st][2]);
            *(uint2*)&dst[swz(row, mbase + 4 * l4)] = make_uint2(lo, hi);
        }

        // tail column t=128: q8's 16 channels, taps k=0 (row 132-DD), k=1 (row 132)
        {
            const int rowA = 132 - DD;
            uint4v va0 = *(const uint4v*)&src[swz(rowA, tc0)];
            uint4v va1 = *(const uint4v*)&src[swz(rowA, tc0 + 8)];
            uint4v vb0 = *(const uint4v*)&src[swz(132, tc0)];
            uint4v vb1 = *(const uint4v*)&src[swz(132, tc0 + 8)];
            float tsum = 0.f;
#pragma unroll
            for (int i = 0; i < 4; ++i) {
                tsum += bflo(va0[i]) * bflo(twA[i])     + bfhi(va0[i]) * bfhi(twA[i]);
                tsum += bflo(va1[i]) * bflo(twA[4 + i]) + bfhi(va1[i]) * bfhi(twA[4 + i]);
                tsum += bflo(vb0[i]) * bflo(twB[i])     + bfhi(vb0[i]) * bfhi(twB[i]);
                tsum += bflo(vb1[i]) * bflo(twB[4 + i]) + bfhi(vb1[i]) * bfhi(twB[4 + i]);
            }
            tsum += __shfl_xor(tsum, 1);
            tsum += __shfl_xor(tsum, 2);
            tsum += __shfl_xor(tsum, 4);
            if (q8 == 0) {
                h128reg = fmaxf(tsum + cb_t, 0.f) + h128reg;
                dst[swz(132, o_t)] = one_bf(h128reg);
            }
        }
        __syncthreads();
    };

    int cur = 0;
    for (int i = 0; i < 4;   ++i) { step(IC<1>{}, cur); cur ^= 1; }
    for (int i = 0; i < 4;   ++i) { step(IC<2>{}, cur); cur ^= 1; }
    for (int i = 0; i < 123; ++i) { step(IC<4>{}, cur); cur ^= 1; }

    // ---------------- output head ----------------
    const short* fin = hbuf + cur * HSTRIDE;
    const int g = tid & 3;
    for (int tt = tid >> 2; tt < 129; tt += 256) {
        const int row = tt + 4;
        float hq[32];
#pragma unroll
        for (int j = 0; j < 4; ++j) {
            uint4v v = *(const uint4v*)&fin[swz(row, 32 * g + 8 * j)];
#pragma unroll
            for (int i = 0; i < 4; ++i) {
                hq[j*8 + 2*i]     = bflo(v[i]);
                hq[j*8 + 2*i + 1] = bfhi(v[i]);
            }
        }
#pragma unroll
        for (int v = 0; v < 10; ++v) {
            float s = 0.f;
#pragma unroll
            for (int i = 0; i < 16; ++i) {
                unsigned w = owP[v][16 * g + i];
                s += hq[2*i] * bflo(w) + hq[2*i + 1] * bfhi(w);
            }
            s += __shfl_xor(s, 1);
            s += __shfl_xor(s, 2);
            if (g == 0) out[(b * 129 + tt) * 10 + v] = s + obS[v];
        }
    }
}

extern "C" void kernel_launch(void* const* d_in, const int* in_sizes, int n_in,
                              void* d_out, int out_size, void* d_ws, size_t ws_size,
                              hipStream_t stream) {
    const int*   x      = (const int*)d_in[0];
    const float* emb_w  = (const float*)d_in[1];
    const float* red_w  = (const float*)d_in[2];
    const float* red_b  = (const float*)d_in[3];
    const float* conv_w = (const float*)d_in[4];
    const float* conv_b = (const float*)d_in[5];
    const float* out_w  = (const float*)d_in[6];
    const float* out_b  = (const float*)d_in[7];
    (void)in_sizes; (void)n_in; (void)d_ws; (void)ws_size; (void)out_size;
    vgt_kernel<<<32, 1024, 0, stream>>>(x, emb_w, red_w, red_b, conv_w, conv_b,
                                        out_w, out_b, (float*)d_out);
}

// Round 6
// 1006.984 us; speedup vs baseline: 1.3389x; 1.0007x over previous
//
#include <hip/hip_runtime.h>

typedef __attribute__((ext_vector_type(8))) short short8;
typedef __attribute__((ext_vector_type(4))) float vf4;
typedef __attribute__((ext_vector_type(4))) unsigned uint4v;

#define NT 1024
#define HROWS 144
#define HSTRIDE (HROWS * 128)   // shorts per buffer

template<int N> struct IC { static constexpr int v = N; };

static __device__ __forceinline__ unsigned packbf(float hi, float lo) {
    return __builtin_amdgcn_perm(__float_as_uint(hi) + 0x8000u,
                                 __float_as_uint(lo) + 0x8000u, 0x07060302u);
}
static __device__ __forceinline__ short one_bf(float f) {
    return (short)((__float_as_uint(f) + 0x8000u) >> 16);
}
static __device__ __forceinline__ float bflo(unsigned u) { return __uint_as_float(u << 16); }
static __device__ __forceinline__ float bfhi(unsigned u) { return __uint_as_float(u & 0xffff0000u); }

static __device__ __forceinline__ int swz(int row, int c) {
    return (row * 128 + c) ^ ((row & 7) << 3);
}

__global__ __launch_bounds__(1024, 4)
void vgt_kernel(const int* __restrict__ x,
                const float* __restrict__ emb_w,
                const float* __restrict__ red_w,
                const float* __restrict__ red_b,
                const float* __restrict__ conv_w,
                const float* __restrict__ conv_b,
                const float* __restrict__ out_w,
                const float* __restrict__ out_b,
                float* __restrict__ out)
{
    __shared__ short    hbuf[2 * HSTRIDE];   // ping-pong bf16 h images (73728 B)
    __shared__ float    m1[128][10];
    __shared__ float    m2[128][10];
    __shared__ unsigned owP[10][64];
    __shared__ float    cbS[128];
    __shared__ float    rbS[128];
    __shared__ float    obS[16];
    __shared__ int      xbS[256];

    const int b    = blockIdx.x;
    const int tid  = threadIdx.x;
    const int lane = tid & 63;
    const int wv   = tid >> 6;          // 0..15
    const int wm8  = wv & 7;            // M tile: 16 output channels
    const int wt2  = wv >> 3;           // t half: 64 columns
    const int mbase = wm8 * 16;
    const int tb0   = wt2 * 64;
    const int l15  = lane & 15;
    const int l4   = lane >> 4;         // 0..3

    // ---------------- prologue ----------------
    for (int i = tid; i < HSTRIDE; i += NT) ((int*)hbuf)[i] = 0;
    if (tid < 256) xbS[tid] = x[b * 256 + tid];
    if (tid < 128) { cbS[tid] = conv_b[tid]; rbS[tid] = red_b[tid]; }
    if (tid < 16)  obS[tid] = (tid < 10) ? out_b[tid] : 0.f;
    if (tid < 640) {
        int v = tid >> 6, j = tid & 63;
        owP[v][j] = packbf(out_w[v * 128 + 2 * j + 1], out_w[v * 128 + 2 * j]);
    }
    // embedding + reducer collapsed into two 128x10 tables
    for (int e = tid; e < 2560; e += NT) {
        int o = e / 20, col = e % 20, v = col % 10;
        const float4* rw = (const float4*)(red_w + o * 256 + ((col < 10) ? 0 : 128));
        const float4* ew = (const float4*)(emb_w + v * 128);
        float s = 0.f;
#pragma unroll 8
        for (int c = 0; c < 32; ++c) {
            float4 a = rw[c], e4 = ew[c];
            s += a.x * e4.x + a.y * e4.y + a.z * e4.z + a.w * e4.w;
        }
        if (col < 10) m1[o][v] = s; else m2[o][v] = s;
    }

    // conv-weight A fragments (16x16x32 layout): aw[kk*4+kb]
    // lane holds A[mbase + l15][kb*32 + l4*8 + j], tap kk   -> 48 VGPRs
    short8 aw[12];
#pragma unroll
    for (int s = 0; s < 12; ++s) {
        int kk = s >> 2, kb = s & 3;
        int o = mbase + l15;
        int c0 = kb * 32 + l4 * 8;
        short8 v;
#pragma unroll
        for (int j = 0; j < 8; ++j)
            v[j] = one_bf(conv_w[(o * 128 + c0 + j) * 3 + kk]);
        aw[s] = v;
    }

    // tail column (t=128): 8 threads per o; q8 owns 16 channels, both taps (16 regs)
    const int o_t = tid >> 3, q8 = tid & 7;
    const int tc0 = q8 * 16;
    unsigned twA[8], twB[8];
#pragma unroll
    for (int i = 0; i < 8; ++i) {
        int c = tc0 + 2 * i;
        twA[i] = packbf(conv_w[(o_t * 128 + c + 1) * 3 + 0],
                        conv_w[(o_t * 128 + c) * 3 + 0]);
        twB[i] = packbf(conv_w[(o_t * 128 + c + 1) * 3 + 1],
                        conv_w[(o_t * 128 + c) * 3 + 1]);
    }
    float h128reg = 0.f;

    __syncthreads();

    const float cb_t = cbS[o_t];
    float bias4[4];
#pragma unroll
    for (int r = 0; r < 4; ++r) bias4[r] = cbS[mbase + l4 * 4 + r];

    // initial h: fp32 master hr[st][r] covers o = mbase+4*l4+r, t = tb0+st*16+l15
    float hr[4][4];
#pragma unroll
    for (int st = 0; st < 4; ++st) {
        int t = tb0 + st * 16 + l15;
        int xv1 = xbS[t], xv2 = xbS[t + 128];
#pragma unroll
        for (int r = 0; r < 4; ++r) {
            int o = mbase + l4 * 4 + r;
            float s = m1[o][xv1] + m2[o][xv2] + rbS[o];
            hr[st][r] = s > 0.f ? s : 0.f;
        }
        int row = t + 4;
        unsigned lo = packbf(hr[st][1], hr[st][0]);
        unsigned hi = packbf(hr[st][3], hr[st][2]);
        *(uint2*)&hbuf[swz(row, mbase + 4 * l4)] = make_uint2(lo, hi);
    }
    __syncthreads();

    // ------------- residual conv step: read src, write dst, ONE barrier -------------
    auto step = [&](auto DDC, int cur) {
        constexpr int DD = decltype(DDC)::v;
        const short* src = hbuf + cur * HSTRIDE;
        short*       dst = hbuf + (cur ^ 1) * HSTRIDE;

#pragma unroll
        for (int st = 0; st < 4; ++st) {
            const int tcol = tb0 + st * 16;
            vf4 acc;
            acc[0] = bias4[0]; acc[1] = bias4[1];
            acc[2] = bias4[2]; acc[3] = bias4[3];
#pragma unroll
            for (int kk = 0; kk < 3; ++kk) {
                const int row = tcol + l15 + 4 + (kk - 1) * DD;
#pragma unroll
                for (int kb = 0; kb < 4; ++kb) {
                    short8 bfr = *(const short8*)&src[swz(row, kb * 32 + l4 * 8)];
                    acc = __builtin_amdgcn_mfma_f32_16x16x32_bf16(aw[kk * 4 + kb], bfr, acc, 0, 0, 0);
                }
            }
            const int row = tcol + l15 + 4;
            hr[st][0] += fmaxf(acc[0], 0.f);
            hr[st][1] += fmaxf(acc[1], 0.f);
            hr[st][2] += fmaxf(acc[2], 0.f);
            hr[st][3] += fmaxf(acc[3], 0.f);
            unsigned lo = packbf(hr[st][1], hr[st][0]);
            unsigned hi = packbf(hr[st][3], hr[st][2]);
            *(uint2*)&dst[swz(row, mbase + 4 * l4)] = make_uint2(lo, hi);
        }

        // tail column t=128: q8's 16 channels, taps k=0 (row 132-DD), k=1 (row 132)
        {
            const int rowA = 132 - DD;
            uint4v va0 = *(const uint4v*)&src[swz(rowA, tc0)];
            uint4v va1 = *(const uint4v*)&src[swz(rowA, tc0 + 8)];
            uint4v vb0 = *(const uint4v*)&src[swz(132, tc0)];
            uint4v vb1 = *(const uint4v*)&src[swz(132, tc0 + 8)];
            float tsum = 0.f;
#pragma unroll
            for (int i = 0; i < 4; ++i) {
                tsum += bflo(va0[i]) * bflo(twA[i])     + bfhi(va0[i]) * bfhi(twA[i]);
                tsum += bflo(va1[i]) * bflo(twA[4 + i]) + bfhi(va1[i]) * bfhi(twA[4 + i]);
                tsum += bflo(vb0[i]) * bflo(twB[i])     + bfhi(vb0[i]) * bfhi(twB[i]);
                tsum += bflo(vb1[i]) * bflo(twB[4 + i]) + bfhi(vb1[i]) * bfhi(twB[4 + i]);
            }
            tsum += __shfl_xor(tsum, 1);
            tsum += __shfl_xor(tsum, 2);
            tsum += __shfl_xor(tsum, 4);
            if (q8 == 0) {
                h128reg = fmaxf(tsum + cb_t, 0.f) + h128reg;
                dst[swz(132, o_t)] = one_bf(h128reg);
            }
        }
        __syncthreads();
    };

    int cur = 0;
    for (int i = 0; i < 4;   ++i) { step(IC<1>{}, cur); cur ^= 1; }
    for (int i = 0; i < 4;   ++i) { step(IC<2>{}, cur); cur ^= 1; }
    for (int i = 0; i < 123; ++i) { step(IC<4>{}, cur); cur ^= 1; }

    // ---------------- output head ----------------
    const short* fin = hbuf + cur * HSTRIDE;
    const int g = tid & 3;
    for (int tt = tid >> 2; tt < 129; tt += 256) {
        const int row = tt + 4;
        float hq[32];
#pragma unroll
        for (int j = 0; j < 4; ++j) {
            uint4v v = *(const uint4v*)&fin[swz(row, 32 * g + 8 * j)];
#pragma unroll
            for (int i = 0; i < 4; ++i) {
                hq[j*8 + 2*i]     = bflo(v[i]);
                hq[j*8 + 2*i + 1] = bfhi(v[i]);
            }
        }
#pragma unroll
        for (int v = 0; v < 10; ++v) {
            float s = 0.f;
#pragma unroll
            for (int i = 0; i < 16; ++i) {
                unsigned w = owP[v][16 * g + i];
                s += hq[2*i] * bflo(w) + hq[2*i + 1] * bfhi(w);
            }
            s += __shfl_xor(s, 1);
            s += __shfl_xor(s, 2);
            if (g == 0) out[(b * 129 + tt) * 10 + v] = s + obS[v];
        }
    }
}

extern "C" void kernel_launch(void* const* d_in, const int* in_sizes, int n_in,
                              void* d_out, int out_size, void* d_ws, size_t ws_size,
                              hipStream_t stream) {
    const int*   x      = (const int*)d_in[0];
    const float* emb_w  = (const float*)d_in[1];
    const float* red_w  = (const float*)d_in[2];
    const float* red_b  = (const float*)d_in[3];
    const float* conv_w = (const float*)d_in[4];
    const float* conv_b = (const float*)d_in[5];
    const float* out_w  = (const float*)d_in[6];
    const float* out_b  = (const float*)d_in[7];
    (void)in_sizes; (void)n_in; (void)d_ws; (void)ws_size; (void)out_size;
    vgt_kernel<<<32, 1024, 0, stream>>>(x, emb_w, red_w, red_b, conv_w, conv_b,
                                        out_w, out_b, (float*)d_out);
}

// Round 7
// 1004.768 us; speedup vs baseline: 1.3419x; 1.0022x over previous
//
#include <hip/hip_runtime.h>

typedef __attribute__((ext_vector_type(8))) short short8;
typedef __attribute__((ext_vector_type(4))) float vf4;
typedef __attribute__((ext_vector_type(4))) unsigned uint4v;

#define NT 1024
#define HROWS 144
#define HSTRIDE (HROWS * 128)   // shorts per buffer

template<int N> struct IC { static constexpr int v = N; };

static __device__ __forceinline__ unsigned packbf(float hi, float lo) {
    return __builtin_amdgcn_perm(__float_as_uint(hi) + 0x8000u,
                                 __float_as_uint(lo) + 0x8000u, 0x07060302u);
}
static __device__ __forceinline__ short one_bf(float f) {
    return (short)((__float_as_uint(f) + 0x8000u) >> 16);
}
static __device__ __forceinline__ float bflo(unsigned u) { return __uint_as_float(u << 16); }
static __device__ __forceinline__ float bfhi(unsigned u) { return __uint_as_float(u & 0xffff0000u); }

static __device__ __forceinline__ int swz(int row, int c) {
    return (row * 128 + c) ^ ((row & 7) << 3);
}

__attribute__((amdgpu_waves_per_eu(4, 4)))
__global__ __launch_bounds__(1024)
void vgt_kernel(const int* __restrict__ x,
                const float* __restrict__ emb_w,
                const float* __restrict__ red_w,
                const float* __restrict__ red_b,
                const float* __restrict__ conv_w,
                const float* __restrict__ conv_b,
                const float* __restrict__ out_w,
                const float* __restrict__ out_b,
                float* __restrict__ out)
{
    __shared__ short    hbuf[2 * HSTRIDE];   // ping-pong bf16 h images (73728 B)
    __shared__ float    m1[128][10];
    __shared__ float    m2[128][10];
    __shared__ unsigned owP[10][64];
    __shared__ float    cbS[128];
    __shared__ float    rbS[128];
    __shared__ float    obS[16];
    __shared__ int      xbS[256];

    const int b    = blockIdx.x;
    const int tid  = threadIdx.x;
    const int lane = tid & 63;
    const int wv   = tid >> 6;          // 0..15
    const int wm8  = wv & 7;            // M tile: 16 output channels
    const int wt2  = wv >> 3;           // t half: 64 columns
    const int mbase = wm8 * 16;
    const int tb0   = wt2 * 64;
    const int l15  = lane & 15;
    const int l4   = lane >> 4;         // 0..3

    // ---------------- prologue ----------------
    for (int i = tid; i < HSTRIDE; i += NT) ((int*)hbuf)[i] = 0;
    if (tid < 256) xbS[tid] = x[b * 256 + tid];
    if (tid < 128) { cbS[tid] = conv_b[tid]; rbS[tid] = red_b[tid]; }
    if (tid < 16)  obS[tid] = (tid < 10) ? out_b[tid] : 0.f;
    if (tid < 640) {
        int v = tid >> 6, j = tid & 63;
        owP[v][j] = packbf(out_w[v * 128 + 2 * j + 1], out_w[v * 128 + 2 * j]);
    }
    // embedding + reducer collapsed into two 128x10 tables
    for (int e = tid; e < 2560; e += NT) {
        int o = e / 20, col = e % 20, v = col % 10;
        const float4* rw = (const float4*)(red_w + o * 256 + ((col < 10) ? 0 : 128));
        const float4* ew = (const float4*)(emb_w + v * 128);
        float s = 0.f;
#pragma unroll 8
        for (int c = 0; c < 32; ++c) {
            float4 a = rw[c], e4 = ew[c];
            s += a.x * e4.x + a.y * e4.y + a.z * e4.z + a.w * e4.w;
        }
        if (col < 10) m1[o][v] = s; else m2[o][v] = s;
    }

    // conv-weight A fragments (16x16x32 layout): aw[kk*4+kb]
    // lane holds A[mbase + l15][kb*32 + l4*8 + j], tap kk   -> 48 VGPRs
    short8 aw[12];
#pragma unroll
    for (int s = 0; s < 12; ++s) {
        int kk = s >> 2, kb = s & 3;
        int o = mbase + l15;
        int c0 = kb * 32 + l4 * 8;
        short8 v;
#pragma unroll
        for (int j = 0; j < 8; ++j)
            v[j] = one_bf(conv_w[(o * 128 + c0 + j) * 3 + kk]);
        aw[s] = v;
    }

    // tail column (t=128): 8 threads per o; q8 owns 16 channels, both taps (16 regs)
    const int o_t = tid >> 3, q8 = tid & 7;
    const int tc0 = q8 * 16;
    unsigned twA[8], twB[8];
#pragma unroll
    for (int i = 0; i < 8; ++i) {
        int c = tc0 + 2 * i;
        twA[i] = packbf(conv_w[(o_t * 128 + c + 1) * 3 + 0],
                        conv_w[(o_t * 128 + c) * 3 + 0]);
        twB[i] = packbf(conv_w[(o_t * 128 + c + 1) * 3 + 1],
                        conv_w[(o_t * 128 + c) * 3 + 1]);
    }
    float h128reg = 0.f;

    __syncthreads();

    const float cb_t = cbS[o_t];
    float bias4[4];
#pragma unroll
    for (int r = 0; r < 4; ++r) bias4[r] = cbS[mbase + l4 * 4 + r];

    // initial h: fp32 master hr[st][r] covers o = mbase+4*l4+r, t = tb0+st*16+l15
    float hr[4][4];
#pragma unroll
    for (int st = 0; st < 4; ++st) {
        int t = tb0 + st * 16 + l15;
        int xv1 = xbS[t], xv2 = xbS[t + 128];
#pragma unroll
        for (int r = 0; r < 4; ++r) {
            int o = mbase + l4 * 4 + r;
            float s = m1[o][xv1] + m2[o][xv2] + rbS[o];
            hr[st][r] = s > 0.f ? s : 0.f;
        }
        int row = t + 4;
        unsigned lo = packbf(hr[st][1], hr[st][0]);
        unsigned hi = packbf(hr[st][3], hr[st][2]);
        *(uint2*)&hbuf[swz(row, mbase + 4 * l4)] = make_uint2(lo, hi);
    }
    __syncthreads();

    // ------------- residual conv step: read src, write dst, ONE barrier -------------
    auto step = [&](auto DDC, int cur) {
        constexpr int DD = decltype(DDC)::v;
        const short* src = hbuf + cur * HSTRIDE;
        short*       dst = hbuf + (cur ^ 1) * HSTRIDE;

#pragma unroll
        for (int st = 0; st < 4; ++st) {
            const int tcol = tb0 + st * 16;
            vf4 acc;
            acc[0] = bias4[0]; acc[1] = bias4[1];
            acc[2] = bias4[2]; acc[3] = bias4[3];
#pragma unroll
            for (int kk = 0; kk < 3; ++kk) {
                const int row = tcol + l15 + 4 + (kk - 1) * DD;
#pragma unroll
                for (int kb = 0; kb < 4; ++kb) {
                    short8 bfr = *(const short8*)&src[swz(row, kb * 32 + l4 * 8)];
                    acc = __builtin_amdgcn_mfma_f32_16x16x32_bf16(aw[kk * 4 + kb], bfr, acc, 0, 0, 0);
                }
            }
            const int row = tcol + l15 + 4;
            hr[st][0] += fmaxf(acc[0], 0.f);
            hr[st][1] += fmaxf(acc[1], 0.f);
            hr[st][2] += fmaxf(acc[2], 0.f);
            hr[st][3] += fmaxf(acc[3], 0.f);
            unsigned lo = packbf(hr[st][1], hr[st][0]);
            unsigned hi = packbf(hr[st][3], hr[st][2]);
            *(uint2*)&dst[swz(row, mbase + 4 * l4)] = make_uint2(lo, hi);
        }

        // tail column t=128: q8's 16 channels, taps k=0 (row 132-DD), k=1 (row 132)
        {
            const int rowA = 132 - DD;
            uint4v va0 = *(const uint4v*)&src[swz(rowA, tc0)];
            uint4v va1 = *(const uint4v*)&src[swz(rowA, tc0 + 8)];
            uint4v vb0 = *(const uint4v*)&src[swz(132, tc0)];
            uint4v vb1 = *(const uint4v*)&src[swz(132, tc0 + 8)];
            float tsum = 0.f;
#pragma unroll
            for (int i = 0; i < 4; ++i) {
                tsum += bflo(va0[i]) * bflo(twA[i])     + bfhi(va0[i]) * bfhi(twA[i]);
                tsum += bflo(va1[i]) * bflo(twA[4 + i]) + bfhi(va1[i]) * bfhi(twA[4 + i]);
                tsum += bflo(vb0[i]) * bflo(twB[i])     + bfhi(vb0[i]) * bfhi(twB[i]);
                tsum += bflo(vb1[i]) * bflo(twB[4 + i]) + bfhi(vb1[i]) * bfhi(twB[4 + i]);
            }
            tsum += __shfl_xor(tsum, 1);
            tsum += __shfl_xor(tsum, 2);
            tsum += __shfl_xor(tsum, 4);
            if (q8 == 0) {
                h128reg = fmaxf(tsum + cb_t, 0.f) + h128reg;
                dst[swz(132, o_t)] = one_bf(h128reg);
            }
        }
        __syncthreads();
    };

    int cur = 0;
    for (int i = 0; i < 4;   ++i) { step(IC<1>{}, cur); cur ^= 1; }
    for (int i = 0; i < 4;   ++i) { step(IC<2>{}, cur); cur ^= 1; }
    for (int i = 0; i < 123; ++i) { step(IC<4>{}, cur); cur ^= 1; }

    // ---------------- output head ----------------
    const short* fin = hbuf + cur * HSTRIDE;
    const int g = tid & 3;
    for (int tt = tid >> 2; tt < 129; tt += 256) {
        const int row = tt + 4;
        float hq[32];
#pragma unroll
        for (int j = 0; j < 4; ++j) {
            uint4v v = *(const uint4v*)&fin[swz(row, 32 * g + 8 * j)];
#pragma unroll
            for (int i = 0; i < 4; ++i) {
                hq[j*8 + 2*i]     = bflo(v[i]);
                hq[j*8 + 2*i + 1] = bfhi(v[i]);
            }
        }
#pragma unroll
        for (int v = 0; v < 10; ++v) {
            float s = 0.f;
#pragma unroll
            for (int i = 0; i < 16; ++i) {
                unsigned w = owP[v][16 * g + i];
                s += hq[2*i] * bflo(w) + hq[2*i + 1] * bfhi(w);
            }
            s += __shfl_xor(s, 1);
            s += __shfl_xor(s, 2);
            if (g == 0) out[(b * 129 + tt) * 10 + v] = s + obS[v];
        }
    }
}

extern "C" void kernel_launch(void* const* d_in, const int* in_sizes, int n_in,
                              void* d_out, int out_size, void* d_ws, size_t ws_size,
                              hipStream_t stream) {
    const int*   x      = (const int*)d_in[0];
    const float* emb_w  = (const float*)d_in[1];
    const float* red_w  = (const float*)d_in[2];
    const float* red_b  = (const float*)d_in[3];
    const float* conv_w = (const float*)d_in[4];
    const float* conv_b = (const float*)d_in[5];
    const float* out_w  = (const float*)d_in[6];
    const float* out_b  = (const float*)d_in[7];
    (void)in_sizes; (void)n_in; (void)d_ws; (void)ws_size; (void)out_size;
    vgt_kernel<<<32, 1024, 0, stream>>>(x, emb_w, red_w, red_b, conv_w, conv_b,
                                        out_w, out_b, (float*)d_out);
}

// Round 9
// 913.512 us; speedup vs baseline: 1.4759x; 1.0999x over previous
//
#include <hip/hip_runtime.h>

typedef __attribute__((ext_vector_type(8))) short short8;
typedef __attribute__((ext_vector_type(16))) float f32x16;
typedef __attribute__((ext_vector_type(4))) unsigned uint4v;

#define NT 512
#define IROWS 144
#define ISTRIDE (IROWS * 128)   // shorts per image buffer

template<int N> struct IC { static constexpr int v = N; };
template<bool B> struct BC { static constexpr bool v = B; };

static __device__ __forceinline__ unsigned packbf(float hi, float lo) {
    return __builtin_amdgcn_perm(__float_as_uint(hi) + 0x8000u,
                                 __float_as_uint(lo) + 0x8000u, 0x07060302u);
}
static __device__ __forceinline__ short one_bf(float f) {
    return (short)((__float_as_uint(f) + 0x8000u) >> 16);
}
static __device__ __forceinline__ float bflo(unsigned u) { return __uint_as_float(u << 16); }
static __device__ __forceinline__ float bfhi(unsigned u) { return __uint_as_float(u & 0xffff0000u); }

// bf16 image: short index; rows = t+4; 8-byte-granular swizzle (2-way max on b64)
static __device__ __forceinline__ int swzI(int row, int c) {
    return (row * 128 + c) ^ ((row & 15) << 2);
}
// fp32 master: float index; t in [0,128]; 8-byte-granular swizzle
static __device__ __forceinline__ int swzH(int t, int o) {
    return (t * 128 + o) ^ ((t & 15) << 1);
}

__global__ __launch_bounds__(512, 1)
void vgt_kernel(const int* __restrict__ x,
                const float* __restrict__ emb_w,
                const float* __restrict__ red_w,
                const float* __restrict__ red_b,
                const float* __restrict__ conv_w,
                const float* __restrict__ conv_b,
                const float* __restrict__ out_w,
                const float* __restrict__ out_b,
                float* __restrict__ out)
{
    __shared__ short    img[2 * ISTRIDE];    // 73728 B, ping-pong, rows 133..143 stay zero
    __shared__ float    hrF[129 * 128];      // 66048 B fp32 master, swizzled
    __shared__ float    m1S[128][10];
    __shared__ float    m2S[128][10];
    __shared__ unsigned owP[10][64];
    __shared__ float    cbS[128];
    __shared__ float    rbS[128];
    __shared__ float    obS[16];
    __shared__ int      xbS[256];

    const int b    = blockIdx.x;
    const int tid  = threadIdx.x;
    const int lane = tid & 63;
    const int wv   = tid >> 6;      // 0..7
    const int wm   = wv & 3;        // m-tile
    const int wh   = wv >> 2;       // t-group: 0 -> subtiles {0,1}, 1 -> {2,3,pad}
    const int obase = wm * 32;
    const int l31  = lane & 31;
    const int lhi  = lane >> 5;

    // ---------------- prologue ----------------
    for (int i = tid; i < ISTRIDE; i += NT) ((int*)img)[i] = 0;   // both buffers (int = 2 shorts)
    if (tid < 256) xbS[tid] = x[b * 256 + tid];
    if (tid < 128) { cbS[tid] = conv_b[tid]; rbS[tid] = red_b[tid]; hrF[16384 + tid] = 0.f; }
    if (tid < 16)  obS[tid] = (tid < 10) ? out_b[tid] : 0.f;
    for (int i = tid; i < 640; i += NT) {
        int v = i >> 6, j = i & 63;
        owP[v][j] = packbf(out_w[v * 128 + 2 * j + 1], out_w[v * 128 + 2 * j]);
    }
    // embedding + reducer collapsed into two 128x10 tables
    for (int e = tid; e < 2560; e += NT) {
        int o = e / 20, col = e % 20, v = col % 10;
        const float4* rw = (const float4*)(red_w + o * 256 + ((col < 10) ? 0 : 128));
        const float4* ew = (const float4*)(emb_w + v * 128);
        float s = 0.f;
#pragma unroll 8
        for (int c = 0; c < 32; ++c) {
            float4 a = rw[c], e4 = ew[c];
            s += a.x * e4.x + a.y * e4.y + a.z * e4.z + a.w * e4.w;
        }
        if (col < 10) m1S[o][v] = s; else m2S[o][v] = s;
    }

    // conv-weight A fragments resident in registers: s = kk*8 + cb (96 VGPR)
    short8 aw[24];
#pragma unroll
    for (int s = 0; s < 24; ++s) {
        int kk = s >> 3, cb = s & 7;
        int o = obase + l31;
        int c0 = cb * 16 + lhi * 8;
        short8 v;
#pragma unroll
        for (int j = 0; j < 8; ++j)
            v[j] = one_bf(conv_w[(o * 128 + c0 + j) * 3 + kk]);
        aw[s] = v;
    }
    __syncthreads();

    // initial h into fp32 master + bf16 image (buffer 0)
#pragma unroll
    for (int nn = 0; nn < 2; ++nn) {
        int t = (wh * 2 + nn) * 32 + l31;          // 0..127
        int xv1 = xbS[t], xv2 = xbS[t + 128];
#pragma unroll
        for (int g = 0; g < 4; ++g) {
            int o4 = obase + 8 * g + 4 * lhi;
            float v0 = m1S[o4+0][xv1] + m2S[o4+0][xv2] + rbS[o4+0]; v0 = v0 > 0.f ? v0 : 0.f;
            float v1 = m1S[o4+1][xv1] + m2S[o4+1][xv2] + rbS[o4+1]; v1 = v1 > 0.f ? v1 : 0.f;
            float v2 = m1S[o4+2][xv1] + m2S[o4+2][xv2] + rbS[o4+2]; v2 = v2 > 0.f ? v2 : 0.f;
            float v3 = m1S[o4+3][xv1] + m2S[o4+3][xv2] + rbS[o4+3]; v3 = v3 > 0.f ? v3 : 0.f;
            int h0 = swzH(t, o4), h1 = swzH(t, o4 + 2);
            *(float2*)&hrF[h0] = make_float2(v0, v1);
            *(float2*)&hrF[h1] = make_float2(v2, v3);
            *(uint2*)&img[swzI(t + 4, o4)] = make_uint2(packbf(v1, v0), packbf(v3, v2));
        }
    }
    __syncthreads();

    // ---------------- residual conv steps ----------------
    auto doTile = [&](auto DDC, auto PADC, int tcol, const short* src, short* dst) {
        constexpr int  DD  = decltype(DDC)::v;
        constexpr bool PAD = decltype(PADC)::v;

        f32x16 acc;
#pragma unroll
        for (int g = 0; g < 4; ++g) {
            float4 bv = *(const float4*)&cbS[obase + 8 * g + 4 * lhi];
            acc[4*g+0] = bv.x; acc[4*g+1] = bv.y; acc[4*g+2] = bv.z; acc[4*g+3] = bv.w;
        }
        const int rA = tcol + 4 - DD + l31;
#pragma unroll
        for (int kk = 0; kk < 3; ++kk) {
            int row = rA + kk * DD;
            if (PAD) row = (row > 140) ? 140 : row;   // rows >140 are all-zero territory
#pragma unroll
            for (int cb = 0; cb < 8; ++cb) {
                const int c0 = cb * 16 + lhi * 8;
                uint2 p0 = *(const uint2*)&src[swzI(row, c0)];
                uint2 p1 = *(const uint2*)&src[swzI(row, c0 + 4)];
                uint4v u; u[0] = p0.x; u[1] = p0.y; u[2] = p1.x; u[3] = p1.y;
                acc = __builtin_amdgcn_mfma_f32_32x32x16_bf16(
                        aw[kk * 8 + cb], __builtin_bit_cast(short8, u), acc, 0, 0, 0);
            }
        }
        // epilogue: h = relu(acc) + h  (acc already includes bias)
        if (!PAD || l31 == 0) {
            const int t = PAD ? 128 : (tcol + l31);
            const int row = t + 4;
#pragma unroll
            for (int g = 0; g < 4; ++g) {
                const int o4 = obase + 8 * g + 4 * lhi;
                const int h0 = swzH(t, o4), h1 = swzH(t, o4 + 2);
                float2 ha = *(const float2*)&hrF[h0];
                float2 hb = *(const float2*)&hrF[h1];
                ha.x += fmaxf(acc[4*g+0], 0.f);
                ha.y += fmaxf(acc[4*g+1], 0.f);
                hb.x += fmaxf(acc[4*g+2], 0.f);
                hb.y += fmaxf(acc[4*g+3], 0.f);
                *(float2*)&hrF[h0] = ha;
                *(float2*)&hrF[h1] = hb;
                *(uint2*)&dst[swzI(row, o4)] = make_uint2(packbf(ha.y, ha.x), packbf(hb.y, hb.x));
            }
        }
    };

    auto step = [&](auto DDC, int cur) {
        const short* src = img + cur * ISTRIDE;
        short*       dst = img + (cur ^ 1) * ISTRIDE;
        doTile(DDC, BC<false>{}, (wh * 2 + 0) * 32, src, dst);
        doTile(DDC, BC<false>{}, (wh * 2 + 1) * 32, src, dst);
        if (wh) doTile(DDC, BC<true>{}, 128, src, dst);
        __syncthreads();
    };

    int cur = 0;
    for (int i = 0; i < 4;   ++i) { step(IC<1>{}, cur); cur ^= 1; }
    for (int i = 0; i < 4;   ++i) { step(IC<2>{}, cur); cur ^= 1; }
    for (int i = 0; i < 123; ++i) { step(IC<4>{}, cur); cur ^= 1; }

    // ---------------- output head (from fp32 master) ----------------
    const int g = tid & 3;
    for (int tt = tid >> 2; tt < 129; tt += 128) {
        float hq[32];
#pragma unroll
        for (int j = 0; j < 16; ++j) {
            float2 v = *(const float2*)&hrF[swzH(tt, 32 * g + 2 * j)];
            hq[2*j] = v.x; hq[2*j + 1] = v.y;
        }
#pragma unroll
        for (int v = 0; v < 10; ++v) {
            float s = 0.f;
#pragma unroll
            for (int i = 0; i < 16; ++i) {
                unsigned w = owP[v][16 * g + i];
                s += hq[2*i] * bflo(w) + hq[2*i + 1] * bfhi(w);
            }
            s += __shfl_xor(s, 1);
            s += __shfl_xor(s, 2);
            if (g == 0) out[(b * 129 + tt) * 10 + v] = s + obS[v];
        }
    }
}

extern "C" void kernel_launch(void* const* d_in, const int* in_sizes, int n_in,
                              void* d_out, int out_size, void* d_ws, size_t ws_size,
                              hipStream_t stream) {
    const int*   x      = (const int*)d_in[0];
    const float* emb_w  = (const float*)d_in[1];
    const float* red_w  = (const float*)d_in[2];
    const float* red_b  = (const float*)d_in[3];
    const float* conv_w = (const float*)d_in[4];
    const float* conv_b = (const float*)d_in[5];
    const float* out_w  = (const float*)d_in[6];
    const float* out_b  = (const float*)d_in[7];
    (void)in_sizes; (void)n_in; (void)d_ws; (void)ws_size; (void)out_size;
    vgt_kernel<<<32, 512, 0, stream>>>(x, emb_w, red_w, red_b, conv_w, conv_b,
                                       out_w, out_b, (float*)d_out);
}

// Round 10
// 320.089 us; speedup vs baseline: 4.2122x; 2.8539x over previous
//
#include <hip/hip_runtime.h>

typedef __attribute__((ext_vector_type(8))) short short8;
typedef __attribute__((ext_vector_type(16))) float f32x16;

#define IROWS 144
#define ISTRIDE (IROWS * 128)      // shorts, phase-1 image buffer
#define I2ROWS 40
#define I2STRIDE (I2ROWS * 128)    // shorts, phase-2 image buffer

template<int N> struct IC { static constexpr int v = N; };

static __device__ __forceinline__ unsigned packbf(float hi, float lo) {
    return __builtin_amdgcn_perm(__float_as_uint(hi) + 0x8000u,
                                 __float_as_uint(lo) + 0x8000u, 0x07060302u);
}
static __device__ __forceinline__ unsigned short one_bf(float f) {
    return (unsigned short)((__float_as_uint(f) + 0x8000u) >> 16);
}
static __device__ __forceinline__ float bflo(unsigned u) { return __uint_as_float(u << 16); }
static __device__ __forceinline__ float bfhi(unsigned u) { return __uint_as_float(u & 0xffff0000u); }

// bf16 image swizzle: 16B-granular XOR -> single ds_read_b128 per fragment
static __device__ __forceinline__ int swzB(int row, int c) {
    return row * 128 + (c ^ ((row & 15) << 3));
}
// phase-1 fp32 master swizzle
static __device__ __forceinline__ int swzH(int t, int o) {
    return (t * 128 + o) ^ ((t & 15) << 1);
}

// ================= PHASE 1: steps 0-7 (d=1,d=2), 32 blocks x 256 thr =================
__global__ __launch_bounds__(256, 1)
void vgt_phase1(const int* __restrict__ x,
                const float* __restrict__ emb_w,
                const float* __restrict__ red_w,
                const float* __restrict__ red_b,
                const float* __restrict__ conv_w,
                const float* __restrict__ conv_b,
                unsigned short* __restrict__ gw16)
{
    __shared__ short img[2 * ISTRIDE];     // 73728 B ping-pong
    __shared__ float hrF[129 * 128];       // 66048 B fp32 master
    __shared__ float m1S[128][10];
    __shared__ float m2S[128][10];
    __shared__ float cbS[128];
    __shared__ float rbS[128];
    __shared__ int   xbS[256];

    const int b    = blockIdx.x;
    const int tid  = threadIdx.x;
    const int lane = tid & 63;
    const int wm   = tid >> 6;          // 0..3 = m-tile
    const int obase = wm * 32;
    const int l31  = lane & 31;
    const int lhi  = lane >> 5;

    for (int i = tid; i < ISTRIDE; i += 256) ((int*)img)[i] = 0;   // zero both buffers
    xbS[tid] = x[b * 256 + tid];
    if (tid < 128) { cbS[tid] = conv_b[tid]; rbS[tid] = red_b[tid]; hrF[swzH(128, tid)] = 0.f; }
    for (int e = tid; e < 2560; e += 256) {
        int o = e / 20, col = e % 20, v = col % 10;
        const float4* rw = (const float4*)(red_w + o * 256 + ((col < 10) ? 0 : 128));
        const float4* ew = (const float4*)(emb_w + v * 128);
        float s = 0.f;
#pragma unroll 8
        for (int c = 0; c < 32; ++c) {
            float4 a = rw[c], e4 = ew[c];
            s += a.x * e4.x + a.y * e4.y + a.z * e4.z + a.w * e4.w;
        }
        if (col < 10) m1S[o][v] = s; else m2S[o][v] = s;
    }

    short8 aw[24];
#pragma unroll
    for (int s = 0; s < 24; ++s) {
        int kk = s >> 3, cb = s & 7;
        int o = obase + l31;
        int c0 = cb * 16 + lhi * 8;
        short8 v;
#pragma unroll
        for (int j = 0; j < 8; ++j)
            v[j] = (short)one_bf(conv_w[(o * 128 + c0 + j) * 3 + kk]);
        aw[s] = v;
    }
    __syncthreads();

    // initial h
#pragma unroll
    for (int nn = 0; nn < 4; ++nn) {
        int t = nn * 32 + l31;
        int xv1 = xbS[t], xv2 = xbS[t + 128];
#pragma unroll
        for (int g = 0; g < 4; ++g) {
            int o4 = obase + 8 * g + 4 * lhi;
            float v0 = m1S[o4+0][xv1] + m2S[o4+0][xv2] + rbS[o4+0]; v0 = v0 > 0.f ? v0 : 0.f;
            float v1 = m1S[o4+1][xv1] + m2S[o4+1][xv2] + rbS[o4+1]; v1 = v1 > 0.f ? v1 : 0.f;
            float v2 = m1S[o4+2][xv1] + m2S[o4+2][xv2] + rbS[o4+2]; v2 = v2 > 0.f ? v2 : 0.f;
            float v3 = m1S[o4+3][xv1] + m2S[o4+3][xv2] + rbS[o4+3]; v3 = v3 > 0.f ? v3 : 0.f;
            *(float2*)&hrF[swzH(t, o4)]     = make_float2(v0, v1);
            *(float2*)&hrF[swzH(t, o4 + 2)] = make_float2(v2, v3);
            *(uint2*)&img[swzB(t + 4, o4)]  = make_uint2(packbf(v1, v0), packbf(v3, v2));
        }
    }
    __syncthreads();

    int cur = 0;
    auto doTile3 = [&](auto DDC, bool pad, int tcol, const short* src, short* dst) {
        constexpr int DD = decltype(DDC)::v;
        f32x16 a0, a1, a2;
#pragma unroll
        for (int g = 0; g < 4; ++g) {
            float4 bv = *(const float4*)&cbS[obase + 8 * g + 4 * lhi];
            a0[4*g+0] = bv.x; a0[4*g+1] = bv.y; a0[4*g+2] = bv.z; a0[4*g+3] = bv.w;
            a1[4*g+0] = 0.f; a1[4*g+1] = 0.f; a1[4*g+2] = 0.f; a1[4*g+3] = 0.f;
            a2[4*g+0] = 0.f; a2[4*g+1] = 0.f; a2[4*g+2] = 0.f; a2[4*g+3] = 0.f;
        }
        const int rbase = tcol + 4 + l31 - DD;
#define TAP1(KK, ACC) { int row = rbase + KK * DD; if (pad) row = row > 140 ? 140 : row; \
    _Pragma("unroll") for (int cb = 0; cb < 8; ++cb) { \
        short8 bf = *(const short8*)&src[swzB(row, cb * 16 + lhi * 8)]; \
        ACC = __builtin_amdgcn_mfma_f32_32x32x16_bf16(aw[KK * 8 + cb], bf, ACC, 0, 0, 0); } }
        TAP1(0, a0) TAP1(1, a1) TAP1(2, a2)
#undef TAP1
        if (!pad || l31 == 0) {
            const int t = pad ? 128 : (tcol + l31);
            const int row = t + 4;
#pragma unroll
            for (int g = 0; g < 4; ++g) {
                const int o4 = obase + 8 * g + 4 * lhi;
                const int h0 = swzH(t, o4), h1 = swzH(t, o4 + 2);
                float2 ha = *(const float2*)&hrF[h0];
                float2 hb = *(const float2*)&hrF[h1];
                ha.x += fmaxf(a0[4*g+0] + a1[4*g+0] + a2[4*g+0], 0.f);
                ha.y += fmaxf(a0[4*g+1] + a1[4*g+1] + a2[4*g+1], 0.f);
                hb.x += fmaxf(a0[4*g+2] + a1[4*g+2] + a2[4*g+2], 0.f);
                hb.y += fmaxf(a0[4*g+3] + a1[4*g+3] + a2[4*g+3], 0.f);
                *(float2*)&hrF[h0] = ha;
                *(float2*)&hrF[h1] = hb;
                *(uint2*)&dst[swzB(row, o4)] = make_uint2(packbf(ha.y, ha.x), packbf(hb.y, hb.x));
            }
        }
    };
    auto step1 = [&](auto DDC) {
        const short* src = img + cur * ISTRIDE;
        short*       dst = img + (cur ^ 1) * ISTRIDE;
        doTile3(DDC, false, 0,  src, dst);
        doTile3(DDC, false, 32, src, dst);
        doTile3(DDC, false, 64, src, dst);
        doTile3(DDC, false, 96, src, dst);
        doTile3(DDC, true, 128, src, dst);
        __syncthreads();
        cur ^= 1;
    };
    for (int i = 0; i < 4; ++i) step1(IC<1>{});
    for (int i = 0; i < 4; ++i) step1(IC<2>{});

    // dump h (bf16) to global workspace
    for (int i = tid; i < 16512; i += 256) {
        int t = i >> 7, o = i & 127;
        gw16[b * 16512 + i] = one_bf(hrF[swzH(t, o)]);
    }
}

// ========== PHASE 2: 123 d=4 steps as d=1 on residue lattice, 128 blocks x 256 thr ==========
__global__ __launch_bounds__(256, 1)
void vgt_phase2(const float* __restrict__ conv_w,
                const float* __restrict__ conv_b,
                const float* __restrict__ out_w,
                const float* __restrict__ out_b,
                const unsigned short* __restrict__ gw16,
                float* __restrict__ out)
{
    __shared__ short    img2[2 * I2STRIDE];   // 20480 B ping-pong; rows 0,34+ stay zero
    __shared__ float    hrF2[33 * 128];       // final h slice for head
    __shared__ unsigned owP[10][64];
    __shared__ float    cbS[128];
    __shared__ float    obS[16];

    const int bid = blockIdx.x;
    const int b = bid >> 2, r = bid & 3;
    const int TR = (r == 0) ? 33 : 32;
    const int tid  = threadIdx.x;
    const int lane = tid & 63;
    const int wm   = tid >> 6;
    const int obase = wm * 32;
    const int l31  = lane & 31;
    const int lhi  = lane >> 5;

    for (int i = tid; i < I2STRIDE; i += 256) ((int*)img2)[i] = 0;
    if (tid < 128) cbS[tid] = conv_b[tid];
    if (tid < 16)  obS[tid] = (tid < 10) ? out_b[tid] : 0.f;
    for (int i = tid; i < 640; i += 256) {
        int v = i >> 6, j = i & 63;
        owP[v][j] = packbf(out_w[v * 128 + 2 * j + 1], out_w[v * 128 + 2 * j]);
    }

    short8 aw[24];
#pragma unroll
    for (int s = 0; s < 24; ++s) {
        int kk = s >> 3, cb = s & 7;
        int o = obase + l31;
        int c0 = cb * 16 + lhi * 8;
        short8 v;
#pragma unroll
        for (int j = 0; j < 8; ++j)
            v[j] = (short)one_bf(conv_w[(o * 128 + c0 + j) * 3 + kk]);
        aw[s] = v;
    }

    // fp32 master in registers (C-fragment layout); load from phase-1 dump
    const unsigned short* gb = gw16 + b * 16512;
    float hm[16], ha_[16];
    {
        const int t = 4 * l31 + r;
#pragma unroll
        for (int q = 0; q < 16; ++q) {
            int o = obase + (q & 3) + 8 * (q >> 2) + 4 * lhi;
            hm[q] = bflo((unsigned)gb[t * 128 + o]);
            ha_[q] = (r == 0 && l31 == 0) ? bflo((unsigned)gb[128 * 128 + o]) : 0.f;
        }
    }
    __syncthreads();   // img2 zeroed

    // populate img2 buffer 0
    {
        const int row = l31 + 1;
#pragma unroll
        for (int g = 0; g < 4; ++g) {
            int o4 = obase + 8 * g + 4 * lhi;
            *(uint2*)&img2[swzB(row, o4)] =
                make_uint2(packbf(hm[4*g+1], hm[4*g+0]), packbf(hm[4*g+3], hm[4*g+2]));
            if (r == 0 && l31 == 0)
                *(uint2*)&img2[swzB(33, o4)] =
                    make_uint2(packbf(ha_[4*g+1], ha_[4*g+0]), packbf(ha_[4*g+3], ha_[4*g+2]));
        }
    }
    __syncthreads();

    int cur = 0;
    for (int it = 0; it < 123; ++it) {
        const short* src = img2 + cur * I2STRIDE;
        short*       dst = img2 + (cur ^ 1) * I2STRIDE;

        // main tile: t' = l31 (0..31); source rows = l31 + kk
        f32x16 a0, a1, a2;
#pragma unroll
        for (int g = 0; g < 4; ++g) {
            float4 bv = *(const float4*)&cbS[obase + 8 * g + 4 * lhi];
            a0[4*g+0] = bv.x; a0[4*g+1] = bv.y; a0[4*g+2] = bv.z; a0[4*g+3] = bv.w;
            a1[4*g+0] = 0.f; a1[4*g+1] = 0.f; a1[4*g+2] = 0.f; a1[4*g+3] = 0.f;
            a2[4*g+0] = 0.f; a2[4*g+1] = 0.f; a2[4*g+2] = 0.f; a2[4*g+3] = 0.f;
        }
#define TAP2(KK, ACC) { const int row = l31 + KK; \
    _Pragma("unroll") for (int cb = 0; cb < 8; ++cb) { \
        short8 bf = *(const short8*)&src[swzB(row, cb * 16 + lhi * 8)]; \
        ACC = __builtin_amdgcn_mfma_f32_32x32x16_bf16(aw[KK * 8 + cb], bf, ACC, 0, 0, 0); } }
        TAP2(0, a0) TAP2(1, a1) TAP2(2, a2)
#undef TAP2
        {
            const int row = l31 + 1;
#pragma unroll
            for (int g = 0; g < 4; ++g) {
                hm[4*g+0] += fmaxf(a0[4*g+0] + a1[4*g+0] + a2[4*g+0], 0.f);
                hm[4*g+1] += fmaxf(a0[4*g+1] + a1[4*g+1] + a2[4*g+1], 0.f);
                hm[4*g+2] += fmaxf(a0[4*g+2] + a1[4*g+2] + a2[4*g+2], 0.f);
                hm[4*g+3] += fmaxf(a0[4*g+3] + a1[4*g+3] + a2[4*g+3], 0.f);
                int o4 = obase + 8 * g + 4 * lhi;
                *(uint2*)&dst[swzB(row, o4)] =
                    make_uint2(packbf(hm[4*g+1], hm[4*g+0]), packbf(hm[4*g+3], hm[4*g+2]));
            }
        }

        if (r == 0) {   // appendix: t' = 32 (only l31==0 commits)
            f32x16 c0v, c1v, c2v;
#pragma unroll
            for (int g = 0; g < 4; ++g) {
                float4 bv = *(const float4*)&cbS[obase + 8 * g + 4 * lhi];
                c0v[4*g+0] = bv.x; c0v[4*g+1] = bv.y; c0v[4*g+2] = bv.z; c0v[4*g+3] = bv.w;
                c1v[4*g+0] = 0.f; c1v[4*g+1] = 0.f; c1v[4*g+2] = 0.f; c1v[4*g+3] = 0.f;
                c2v[4*g+0] = 0.f; c2v[4*g+1] = 0.f; c2v[4*g+2] = 0.f; c2v[4*g+3] = 0.f;
            }
#define TAPA(KK, ACC) { int row = 32 + l31 + KK; row = row > 34 ? 34 : row; \
    _Pragma("unroll") for (int cb = 0; cb < 8; ++cb) { \
        short8 bf = *(const short8*)&src[swzB(row, cb * 16 + lhi * 8)]; \
        ACC = __builtin_amdgcn_mfma_f32_32x32x16_bf16(aw[KK * 8 + cb], bf, ACC, 0, 0, 0); } }
            TAPA(0, c0v) TAPA(1, c1v) TAPA(2, c2v)
#undef TAPA
            if (l31 == 0) {
#pragma unroll
                for (int g = 0; g < 4; ++g) {
                    ha_[4*g+0] += fmaxf(c0v[4*g+0] + c1v[4*g+0] + c2v[4*g+0], 0.f);
                    ha_[4*g+1] += fmaxf(c0v[4*g+1] + c1v[4*g+1] + c2v[4*g+1], 0.f);
                    ha_[4*g+2] += fmaxf(c0v[4*g+2] + c1v[4*g+2] + c2v[4*g+2], 0.f);
                    ha_[4*g+3] += fmaxf(c0v[4*g+3] + c1v[4*g+3] + c2v[4*g+3], 0.f);
                    int o4 = obase + 8 * g + 4 * lhi;
                    *(uint2*)&dst[swzB(33, o4)] =
                        make_uint2(packbf(ha_[4*g+1], ha_[4*g+0]), packbf(ha_[4*g+3], ha_[4*g+2]));
                }
            }
        }
        __syncthreads();
        cur ^= 1;
    }

    // dump master to LDS for the head
#pragma unroll
    for (int g = 0; g < 4; ++g) {
        int o4 = obase + 8 * g + 4 * lhi;
        *(float4*)&hrF2[l31 * 128 + o4] = make_float4(hm[4*g+0], hm[4*g+1], hm[4*g+2], hm[4*g+3]);
        if (r == 0 && l31 == 0)
            *(float4*)&hrF2[32 * 128 + o4] = make_float4(ha_[4*g+0], ha_[4*g+1], ha_[4*g+2], ha_[4*g+3]);
    }
    __syncthreads();

    // output head: out[b, 4*t'+r, v]
    const int g4 = tid & 3;
    const int tt = tid >> 2;
    if (tt < TR) {
        float hq[32];
#pragma unroll
        for (int j = 0; j < 8; ++j) {
            float4 v = *(const float4*)&hrF2[tt * 128 + 32 * g4 + 4 * j];
            hq[4*j+0] = v.x; hq[4*j+1] = v.y; hq[4*j+2] = v.z; hq[4*j+3] = v.w;
        }
#pragma unroll
        for (int v = 0; v < 10; ++v) {
            float s = 0.f;
#pragma unroll
            for (int i = 0; i < 16; ++i) {
                unsigned w = owP[v][16 * g4 + i];
                s += hq[2*i] * bflo(w) + hq[2*i+1] * bfhi(w);
            }
            s += __shfl_xor(s, 1);
            s += __shfl_xor(s, 2);
            if (g4 == 0) out[(b * 129 + 4 * tt + r) * 10 + v] = s + obS[v];
        }
    }
}

extern "C" void kernel_launch(void* const* d_in, const int* in_sizes, int n_in,
                              void* d_out, int out_size, void* d_ws, size_t ws_size,
                              hipStream_t stream) {
    const int*   x      = (const int*)d_in[0];
    const float* emb_w  = (const float*)d_in[1];
    const float* red_w  = (const float*)d_in[2];
    const float* red_b  = (const float*)d_in[3];
    const float* conv_w = (const float*)d_in[4];
    const float* conv_b = (const float*)d_in[5];
    const float* out_w  = (const float*)d_in[6];
    const float* out_b  = (const float*)d_in[7];
    (void)in_sizes; (void)n_in; (void)ws_size; (void)out_size;
    unsigned short* gw16 = (unsigned short*)d_ws;   // 32*129*128 bf16 = 1.06 MB
    vgt_phase1<<<32, 256, 0, stream>>>(x, emb_w, red_w, red_b, conv_w, conv_b, gw16);
    vgt_phase2<<<128, 256, 0, stream>>>(conv_w, conv_b, out_w, out_b, gw16, (float*)d_out);
}